// Round 11
// baseline (795.302 us; speedup 1.0000x reference)
//
#include <hip/hip_runtime.h>
#include <hip/hip_bf16.h>

#define EPSF 1e-8f

typedef __attribute__((ext_vector_type(8))) short short8v;
typedef __attribute__((ext_vector_type(4))) float float4v;

// x_t geometry: per (b,icc) region = 4 slots x 457 units x 16B = 29248 B.
//   pos = 23*h + 10*(w&1) + (w>>1)   (h,w input coords 0..19; max 456)
//   byte = slot*7312 + pos*16 + ic8*2
#define XREG 29248
#define XSLOT 7312

static __device__ __forceinline__ unsigned short f2bf_bits(float x)
{
    return __builtin_bit_cast(unsigned short, __float2bfloat16(x));
}

// compile-time A-offset for kidx k (after full unroll)
__device__ constexpr int aoff(int k)
{
    return (23 * (k / 9) + 10 * ((k % 9) & 1) + ((k % 9) >> 1)) * 16;
}

// ---------------------------------------------------------------------------
// Bw2 transform: pc_w f32 [256oc][256ic][81k] -> coalesced per-wave chunks:
//   chunk_id = ((kidx*8+icc)*4+wc)*4+nt ; within chunk lane(slot*16+r16)*8+i
// ---------------------------------------------------------------------------
__global__ __launch_bounds__(256) void k_bw2(const float* __restrict__ pw,
                                             __hip_bfloat16* __restrict__ Bw2)
{
    const int oc = blockIdx.x;
    const int t = threadIdx.x;
    __shared__ unsigned short wl[20736];   // [ic][k] bf16 bits
    for (int i = t; i < 20736; i += 256)
        wl[i] = f2bf_bits(pw[(size_t)oc * 20736 + i]);
    __syncthreads();
    const int r16 = oc & 15, nt = (oc >> 4) & 3, wcq = oc >> 6;
    for (int e = t; e < 2592; e += 256) {
        const int kidx = e >> 5, icc = (e >> 2) & 7, slot = e & 3;
        short8v v;
        #pragma unroll
        for (int i = 0; i < 8; ++i)
            v[i] = (short)wl[(icc * 32 + slot * 8 + i) * 81 + kidx];
        const int chunk = ((kidx * 8 + icc) * 4 + wcq) * 4 + nt;
        *(short8v*)(Bw2 + (size_t)chunk * 512 + (slot * 16 + r16) * 8) = v;
    }
}

// ---------------------------------------------------------------------------
// conv1: image[512,1,28,28] * cw[256,1,9,9] + cb -> relu -> x_t (layout above)
// block = b, 256 threads = c. Image in LDS.
// ---------------------------------------------------------------------------
__global__ __launch_bounds__(256) void k_conv1(const float* __restrict__ img,
                                               const float* __restrict__ cw,
                                               const float* __restrict__ cb,
                                               __hip_bfloat16* __restrict__ xt)
{
    const int b = blockIdx.x;
    const int c = threadIdx.x;
    __shared__ float simg[784];
    for (int i = c; i < 784; i += 256) simg[i] = img[b * 784 + i];
    float wreg[81];
    const float* wp = cw + c * 81;
    #pragma unroll
    for (int k = 0; k < 81; ++k) wreg[k] = wp[k];
    const float bias = cb[c];
    __syncthreads();

    const int icc = c >> 5, slot = (c >> 3) & 3, ic8 = c & 7;
    char* xbase = (char*)xt + ((size_t)b * 8 + icc) * XREG + slot * XSLOT + ic8 * 2;

    for (int h = 0; h < 20; ++h) {
        for (int wg = 0; wg < 5; ++wg) {
            float acc[4] = {bias, bias, bias, bias};
            #pragma unroll
            for (int ky = 0; ky < 9; ++ky) {
                const float* rp = &simg[(h + ky) * 28 + wg * 4];
                float v[12];
                #pragma unroll
                for (int i = 0; i < 12; ++i) v[i] = rp[i];
                #pragma unroll
                for (int kx = 0; kx < 9; ++kx) {
                    const float wv = wreg[ky * 9 + kx];
                    #pragma unroll
                    for (int i = 0; i < 4; ++i)
                        acc[i] = fmaf(v[kx + i], wv, acc[i]);
                }
            }
            #pragma unroll
            for (int i = 0; i < 4; ++i) {
                int w = wg * 4 + i;
                float av = fmaxf(acc[i], 0.f);
                int pos = 23 * h + 10 * (w & 1) + (w >> 1);
                *(unsigned short*)(xbase + pos * 16) = f2bf_bits(av);
            }
        }
    }
}

// ---------------------------------------------------------------------------
// async stage of one icc-chunk (1 image, 29248 B) into LDS via global_load_lds
// ---------------------------------------------------------------------------
__device__ __forceinline__ void stage_x(const __hip_bfloat16* __restrict__ xt,
                                        char* dst, int b, int icc, int t)
{
    const char* base = (const char*)xt + ((size_t)b * 8 + icc) * XREG;
    #pragma unroll
    for (int k = 0; k < 7; ++k) {
        const int unit = t + k * 256;
        __builtin_amdgcn_global_load_lds(
            (const __attribute__((address_space(1))) unsigned int*)(base + unit * 16),
            (__attribute__((address_space(3))) unsigned int*)(dst + unit * 16),
            16, 0, 0);
    }
    if (t < 36) {
        const int unit = 1792 + t;
        __builtin_amdgcn_global_load_lds(
            (const __attribute__((address_space(1))) unsigned int*)(base + unit * 16),
            (__attribute__((address_space(3))) unsigned int*)(dst + unit * 16),
            16, 0, 0);
    }
}

// ---------------------------------------------------------------------------
// conv2 via MFMA: grid 512 (1 b each), 256 thr = 4 waves (wc = 64-oc group).
// LDS dbuf 2x29.2KB -> 2 blocks/CU (independent barrier domains hide the
// per-block stage drain). Register pipeline: B ring-4 (dist 3), A ring-3
// (dist 2), fully unrolled 81-body K-loop (all ring indices compile-time).
// ---------------------------------------------------------------------------
__global__ __launch_bounds__(256, 2) void k_conv2(const __hip_bfloat16* __restrict__ xt,
                                                  const __hip_bfloat16* __restrict__ Bw2,
                                                  const float* __restrict__ pcb,
                                                  float* __restrict__ u)
{
    const int b = blockIdx.x;
    const int t = threadIdx.x;
    const int lane = t & 63, wc = t >> 6;
    const int r16 = lane & 15, slot = lane >> 4;

    __shared__ alignas(16) char xs[2][29248];

    int lc[3];
    #pragma unroll
    for (int mt = 0; mt < 3; ++mt) {
        int hw = mt * 16 + r16;
        if (hw >= 36) hw = 0;
        int h = hw / 6, w = hw - h * 6;
        lc[mt] = 46 * h + w;               // 46 = 2*23 (output stride-2 rows)
    }
    const int abase0 = slot * XSLOT;

    float4v acc[3][4];
    #pragma unroll
    for (int mt = 0; mt < 3; ++mt)
        #pragma unroll
        for (int nt = 0; nt < 4; ++nt)
            acc[mt][nt] = (float4v){0.f, 0.f, 0.f, 0.f};

    stage_x(xt, xs[0], b, 0, t);
    __syncthreads();

    for (int icc = 0; icc < 8; ++icc) {
        const int cur = icc & 1;
        if (icc < 7) stage_x(xt, xs[cur ^ 1], b, icc + 1, t);

        const char* xw = xs[cur];
        const char* apm0 = xw + abase0 + lc[0] * 16;
        const char* apm1 = xw + abase0 + lc[1] * 16;
        const char* apm2 = xw + abase0 + lc[2] * 16;
        const __hip_bfloat16* bp = Bw2 + ((size_t)icc * 4 + wc) * 2048 + lane * 8;

        short8v a[3][3];   // A ring-3, prefetch distance 2
        short8v bv[4][4];  // B ring-4, prefetch distance 3
        #pragma unroll
        for (int pk = 0; pk < 2; ++pk) {
            const int off = aoff(pk);
            a[pk][0] = *(const short8v*)(apm0 + off);
            a[pk][1] = *(const short8v*)(apm1 + off);
            a[pk][2] = *(const short8v*)(apm2 + off);
        }
        #pragma unroll
        for (int pk = 0; pk < 3; ++pk) {
            const __hip_bfloat16* bq = bp + (size_t)pk * 65536;
            bv[pk][0] = *(const short8v*)(bq);
            bv[pk][1] = *(const short8v*)(bq + 512);
            bv[pk][2] = *(const short8v*)(bq + 1024);
            bv[pk][3] = *(const short8v*)(bq + 1536);
        }

        #pragma unroll
        for (int ky = 0; ky < 9; ++ky) {
            #pragma unroll
            for (int kx = 0; kx < 9; ++kx) {
                const int k = ky * 9 + kx;
                const int ca = k % 3, cb = k & 3;
                // prefetches first (targets are free ring slots, not consumed here)
                if (k + 3 <= 80) {
                    const int pb3 = (k + 3) & 3;
                    const __hip_bfloat16* bq = bp + (size_t)(k + 3) * 65536;
                    bv[pb3][0] = *(const short8v*)(bq);
                    bv[pb3][1] = *(const short8v*)(bq + 512);
                    bv[pb3][2] = *(const short8v*)(bq + 1024);
                    bv[pb3][3] = *(const short8v*)(bq + 1536);
                }
                if (k + 2 <= 80) {
                    const int pa2 = (k + 2) % 3;
                    const int off = aoff(k + 2);
                    a[pa2][0] = *(const short8v*)(apm0 + off);
                    a[pa2][1] = *(const short8v*)(apm1 + off);
                    a[pa2][2] = *(const short8v*)(apm2 + off);
                }
                #pragma unroll
                for (int mt = 0; mt < 3; ++mt)
                    #pragma unroll
                    for (int nt = 0; nt < 4; ++nt)
                        acc[mt][nt] = __builtin_amdgcn_mfma_f32_16x16x32_bf16(
                            a[ca][mt], bv[cb][nt], acc[mt][nt], 0, 0, 0);
            }
        }
        __syncthreads();
    }

    // epilogue: D row(hw) = slot*4+i, col(oc) = r16
    #pragma unroll
    for (int mt = 0; mt < 3; ++mt) {
        int hwb = mt * 16 + slot * 4;
        if (hwb < 36) {
            #pragma unroll
            for (int nt = 0; nt < 4; ++nt) {
                int oc = wc * 64 + nt * 16 + r16;
                float pb = pcb[oc];
                float4v v = acc[mt][nt];
                v.x += pb; v.y += pb; v.z += pb; v.w += pb;
                *(float4v*)(u + (size_t)b * 9216 + oc * 36 + hwb) = v;
            }
        }
    }
}

// ---------------------------------------------------------------------------
// squash groups of 8 (in place)
// ---------------------------------------------------------------------------
__global__ void k_squash_u(float* __restrict__ u, int ngroups)
{
    int g = blockIdx.x * blockDim.x + threadIdx.x;
    if (g >= ngroups) return;
    float4v* p = (float4v*)(u + (size_t)g * 8);
    float4v a = p[0], c = p[1];
    float sq = a.x * a.x + a.y * a.y + a.z * a.z + a.w * a.w
             + c.x * c.x + c.y * c.y + c.z * c.z + c.w * c.w;
    float scale = (sq / (1.f + sq)) / sqrtf(sq + EPSF);
    a *= scale; c *= scale;
    p[0] = a; p[1] = c;
}

// ---------------------------------------------------------------------------
// routing: grid 1152 = 144 rc (8 W-rows) x 8 bc (64 images); 256 thr.
// Thread = (oq quarter, image); r-loop serial -> NO cross-lane r-reduce.
// ---------------------------------------------------------------------------
__global__ __launch_bounds__(256, 2) void k_route3(const float* __restrict__ u,
                                                   const float* __restrict__ W,
                                                   const float* __restrict__ vsum,
                                                   float* __restrict__ spart, int iter)
{
    const int bid = blockIdx.x;
    const int rc = bid % 144;
    const int bc = bid / 144;
    const int r0 = rc * 8;
    const int b0 = bc * 64;
    const int t = threadIdx.x;
    const int oq = t & 3;
    const int img = t >> 2;           // 0..63
    const int b = b0 + img;

    __shared__ alignas(16) float Wl[10240];    // 40KB: 8 rows x 320 f4 units, swizzled
    __shared__ alignas(16) float ul[64 * 68];  // 17.4KB: u tile, padded stride 68

    #pragma unroll
    for (int k = 0; k < 10; ++k) {
        int e = t + k * 256;
        int rr = e / 320, rest = e - rr * 320;
        float4v val = *(const float4v*)(W + (size_t)(r0 + rr) * 1280 + rest * 4);
        int es = e ^ ((e >> 3) & 3);
        *(float4v*)(Wl + es * 4) = val;
    }
    #pragma unroll
    for (int k = 0; k < 4; ++k) {
        int e = t + k * 256;
        int im = e >> 4, f4 = e & 15;
        float4v val = *(const float4v*)(u + (size_t)(b0 + im) * 9216 + rc * 64 + f4 * 4);
        *(float4v*)(ul + im * 68 + f4 * 4) = val;
    }
    __syncthreads();

    float4v vv[10];
    if (iter > 0) {
        #pragma unroll
        for (int j = 0; j < 10; ++j)
            vv[j] = *(const float4v*)(vsum + (size_t)b * 160 + j * 16 + oq * 4);
    }

    float4v acc[10];
    #pragma unroll
    for (int j = 0; j < 10; ++j) acc[j] = (float4v){0.f, 0.f, 0.f, 0.f};

    const float* up = ul + img * 68;

    for (int r = 0; r < 8; ++r) {
        float4v u0 = *(const float4v*)(up + r * 8);
        float4v u1 = *(const float4v*)(up + r * 8 + 4);
        float4v uh[10];
        #pragma unroll
        for (int j = 0; j < 10; ++j) {
            #pragma unroll
            for (int oo = 0; oo < 4; ++oo) {
                int un = r * 320 + j * 32 + oq * 8 + oo * 2;
                int i0 = un ^ oq;
                int i1 = i0 ^ 1;
                float4v wlo = *(const float4v*)(Wl + i0 * 4);
                float4v whi = *(const float4v*)(Wl + i1 * 4);
                uh[j][oo] = wlo.x * u0.x + wlo.y * u0.y + wlo.z * u0.z + wlo.w * u0.w
                          + whi.x * u1.x + whi.y * u1.y + whi.z * u1.z + whi.w * u1.w;
            }
        }
        if (iter > 0) {
            float q[10];
            #pragma unroll
            for (int j = 0; j < 10; ++j) {
                float qp = uh[j].x * vv[j].x + uh[j].y * vv[j].y
                         + uh[j].z * vv[j].z + uh[j].w * vv[j].w;
                qp += __shfl_xor(qp, 1);
                qp += __shfl_xor(qp, 2);
                q[j] = qp;
            }
            float mx = q[0];
            #pragma unroll
            for (int j = 1; j < 10; ++j) mx = fmaxf(mx, q[j]);
            float ssum = 0.f;
            float c[10];
            #pragma unroll
            for (int j = 0; j < 10; ++j) { c[j] = __expf(q[j] - mx); ssum += c[j]; }
            float inv = 1.f / ssum;
            #pragma unroll
            for (int j = 0; j < 10; ++j) acc[j] += (c[j] * inv) * uh[j];
        } else {
            #pragma unroll
            for (int j = 0; j < 10; ++j) acc[j] += 0.1f * uh[j];
        }
    }

    float* dst = spart + ((size_t)rc * 512 + b) * 160 + oq * 4;
    #pragma unroll
    for (int j = 0; j < 10; ++j)
        *(float4v*)(dst + j * 16) = acc[j];
}

// ---------------------------------------------------------------------------
// finish: sum 144 partials -> squash -> v; vsum update; iter==2 writes outputs
// ---------------------------------------------------------------------------
__global__ void k_finish(const float* __restrict__ spart, float* __restrict__ vsum,
                         const int* __restrict__ label, float* __restrict__ obj,
                         float* __restrict__ yprob, float* __restrict__ masked, int iter)
{
    const int b = blockIdx.x, t = threadIdx.x;
    if (t < 160) {
        const float* sp = spart + (size_t)b * 160 + t;
        float sv = 0.f;
        #pragma unroll 8
        for (int rc = 0; rc < 144; ++rc)
            sv += sp[(size_t)rc * 81920];
        float sq = sv * sv;
        sq += __shfl_xor(sq, 1); sq += __shfl_xor(sq, 2);
        sq += __shfl_xor(sq, 4); sq += __shfl_xor(sq, 8);
        float v = sv * (sq / (1.f + sq)) / sqrtf(sq + EPSF);
        float pv = (iter > 0) ? vsum[b * 160 + t] : 0.f;
        vsum[b * 160 + t] = pv + v;
        if (iter == 2) {
            obj[b * 160 + t] = v;
            float vv = v * v;
            vv += __shfl_xor(vv, 1); vv += __shfl_xor(vv, 2);
            vv += __shfl_xor(vv, 4); vv += __shfl_xor(vv, 8);
            int j = t >> 4;
            if ((t & 15) == 0) yprob[b * 10 + j] = sqrtf(vv + EPSF);
            masked[b * 160 + t] = (label[b] == j) ? v : 0.f;
        }
    }
}

// ---------------------------------------------------------------------------
// decoder GEMM: C[m,n] = act(bias[n] + sum_k A[m,k]*Wt[n,k]); M=512.
// ---------------------------------------------------------------------------
__global__ void k_mlp(const float* __restrict__ A, const float* __restrict__ Wt,
                      const float* __restrict__ bias, float* __restrict__ C,
                      int N, int K, int act)
{
    const int m0 = blockIdx.x * 32;
    const int n0 = blockIdx.y * 32;
    const int t  = threadIdx.x;
    const int tn = t & 31, tg = t >> 5;
    __shared__ float As[32][33];
    __shared__ float Ws[32][33];
    float acc[4] = {0.f, 0.f, 0.f, 0.f};
    for (int k0 = 0; k0 < K; k0 += 32) {
        __syncthreads();
        for (int idx = t; idx < 1024; idx += 256) {
            int rr = idx >> 5, kk = idx & 31;
            As[rr][kk] = A[(size_t)(m0 + rr) * K + k0 + kk];
            int n = n0 + rr;
            Ws[rr][kk] = (n < N) ? Wt[(size_t)n * K + k0 + kk] : 0.f;
        }
        __syncthreads();
        #pragma unroll 8
        for (int kk = 0; kk < 32; ++kk) {
            float bv = Ws[tn][kk];
            #pragma unroll
            for (int i = 0; i < 4; ++i)
                acc[i] += As[tg * 4 + i][kk] * bv;
        }
    }
    int n = n0 + tn;
    if (n < N) {
        float bs = bias[n];
        #pragma unroll
        for (int i = 0; i < 4; ++i) {
            float vv = acc[i] + bs;
            vv = (act == 0) ? fmaxf(vv, 0.f) : 1.f / (1.f + expf(-vv));
            C[(size_t)(m0 + tg * 4 + i) * N + n] = vv;
        }
    }
}

// ---------------------------------------------------------------------------
extern "C" void kernel_launch(void* const* d_in, const int* in_sizes, int n_in,
                              void* d_out, int out_size, void* d_ws, size_t ws_size,
                              hipStream_t stream)
{
    const float* image  = (const float*)d_in[0];
    const int*   label  = (const int*)  d_in[1];
    const float* conv_w = (const float*)d_in[2];
    const float* conv_b = (const float*)d_in[3];
    const float* pc_w   = (const float*)d_in[4];
    const float* pc_b   = (const float*)d_in[5];
    const float* Wrt    = (const float*)d_in[6];
    const float* dw1 = (const float*)d_in[7];
    const float* db1 = (const float*)d_in[8];
    const float* dw2 = (const float*)d_in[9];
    const float* db2 = (const float*)d_in[10];
    const float* dw3 = (const float*)d_in[11];
    const float* db3 = (const float*)d_in[12];
    float* out = (float*)d_out;

    char* p = (char*)d_ws;
    __hip_bfloat16* xt  = (__hip_bfloat16*)p; p += (size_t)512 * 8 * XREG; // 119.8 MB
    float* u      = (float*)p; p += 18874368;
    __hip_bfloat16* Bw2 = (__hip_bfloat16*)p; p += 10616832;
    float* vsum   = (float*)p; p += 327680;
    float* masked = (float*)p; p += 327680;
    float* h1     = (float*)p; p += 1048576;
    float* h2     = (float*)p; p += 2097152;

    // spart [144][512][160] f32 (47.2 MB) aliases xt (dead after k_conv2,
    // fully rewritten by conv1 each launch -> deterministic across replays).
    float* spart = (float*)xt;

    float* obj   = out;            // [512,10,16,1]
    float* recon = out + 81920;    // [512,1,28,28]
    float* yprob = out + 483328;   // [512,10]

    k_bw2<<<256, 256, 0, stream>>>(pc_w, Bw2);
    k_conv1<<<512, 256, 0, stream>>>(image, conv_w, conv_b, xt);
    k_conv2<<<512, 256, 0, stream>>>(xt, Bw2, pc_b, u);
    k_squash_u<<<2304, 256, 0, stream>>>(u, 589824);
    for (int it = 0; it < 3; ++it) {
        k_route3<<<1152, 256, 0, stream>>>(u, Wrt, vsum, spart, it);
        k_finish<<<512, 192, 0, stream>>>(spart, vsum, label, obj, yprob, masked, it);
    }
    k_mlp<<<dim3(16, 16), 256, 0, stream>>>(masked, dw1, db1, h1, 512, 160, 0);
    k_mlp<<<dim3(16, 32), 256, 0, stream>>>(h1, dw2, db2, h2, 1024, 512, 0);
    k_mlp<<<dim3(16, 25), 256, 0, stream>>>(h2, dw3, db3, recon, 784, 1024, 1);
}

// Round 12
// 769.509 us; speedup vs baseline: 1.0335x; 1.0335x over previous
//
#include <hip/hip_runtime.h>
#include <hip/hip_bf16.h>

#define EPSF 1e-8f

typedef __attribute__((ext_vector_type(8))) short short8v;
typedef __attribute__((ext_vector_type(4))) float float4v;

// x_t geometry: per (b,icc) region = 4 slots x 457 units x 16B = 29248 B.
//   pos = 23*h + 10*(w&1) + (w>>1)   (h,w input coords 0..19; max 456)
//   byte = slot*7312 + pos*16 + ic8*2
#define XREG 29248
#define XSLOT 7312

static __device__ __forceinline__ unsigned short f2bf_bits(float x)
{
    return __builtin_bit_cast(unsigned short, __float2bfloat16(x));
}

// ---------------------------------------------------------------------------
// Bw2 transform: pc_w f32 [256oc][256ic][81k] -> coalesced per-wave chunks:
//   chunk_id = ((kidx*8+icc)*4+WC)*4+nt ; within chunk lane(slot*16+r16)*8+i
// ---------------------------------------------------------------------------
__global__ __launch_bounds__(256) void k_bw2(const float* __restrict__ pw,
                                             __hip_bfloat16* __restrict__ Bw2)
{
    const int oc = blockIdx.x;
    const int t = threadIdx.x;
    __shared__ unsigned short wl[20736];   // [ic][k] bf16 bits
    for (int i = t; i < 20736; i += 256)
        wl[i] = f2bf_bits(pw[(size_t)oc * 20736 + i]);
    __syncthreads();
    const int r16 = oc & 15, nt = (oc >> 4) & 3, wcq = oc >> 6;
    for (int e = t; e < 2592; e += 256) {
        const int kidx = e >> 5, icc = (e >> 2) & 7, slot = e & 3;
        short8v v;
        #pragma unroll
        for (int i = 0; i < 8; ++i)
            v[i] = (short)wl[(icc * 32 + slot * 8 + i) * 81 + kidx];
        const int chunk = ((kidx * 8 + icc) * 4 + wcq) * 4 + nt;
        *(short8v*)(Bw2 + (size_t)chunk * 512 + (slot * 16 + r16) * 8) = v;
    }
}

// ---------------------------------------------------------------------------
// conv1: image[512,1,28,28] * cw[256,1,9,9] + cb -> relu -> x_t (layout above)
// block = b, 256 threads = c. Image in LDS.
// ---------------------------------------------------------------------------
__global__ __launch_bounds__(256) void k_conv1(const float* __restrict__ img,
                                               const float* __restrict__ cw,
                                               const float* __restrict__ cb,
                                               __hip_bfloat16* __restrict__ xt)
{
    const int b = blockIdx.x;
    const int c = threadIdx.x;
    __shared__ float simg[784];
    for (int i = c; i < 784; i += 256) simg[i] = img[b * 784 + i];
    float wreg[81];
    const float* wp = cw + c * 81;
    #pragma unroll
    for (int k = 0; k < 81; ++k) wreg[k] = wp[k];
    const float bias = cb[c];
    __syncthreads();

    const int icc = c >> 5, slot = (c >> 3) & 3, ic8 = c & 7;
    char* xbase = (char*)xt + ((size_t)b * 8 + icc) * XREG + slot * XSLOT + ic8 * 2;

    for (int h = 0; h < 20; ++h) {
        for (int wg = 0; wg < 5; ++wg) {
            float acc[4] = {bias, bias, bias, bias};
            #pragma unroll
            for (int ky = 0; ky < 9; ++ky) {
                const float* rp = &simg[(h + ky) * 28 + wg * 4];
                float v[12];
                #pragma unroll
                for (int i = 0; i < 12; ++i) v[i] = rp[i];
                #pragma unroll
                for (int kx = 0; kx < 9; ++kx) {
                    const float wv = wreg[ky * 9 + kx];
                    #pragma unroll
                    for (int i = 0; i < 4; ++i)
                        acc[i] = fmaf(v[kx + i], wv, acc[i]);
                }
            }
            #pragma unroll
            for (int i = 0; i < 4; ++i) {
                int w = wg * 4 + i;
                float av = fmaxf(acc[i], 0.f);
                int pos = 23 * h + 10 * (w & 1) + (w >> 1);
                *(unsigned short*)(xbase + pos * 16) = f2bf_bits(av);
            }
        }
    }
}

// ---------------------------------------------------------------------------
// async stage of one icc-chunk for 4 images (4 x 29248 B, contiguous in LDS)
// per-lane global src (allowed), linear LDS dst (required).
// ---------------------------------------------------------------------------
__device__ __forceinline__ void stage_x4(const __hip_bfloat16* __restrict__ xt,
                                         char* dst, int b0, int icc, int t)
{
    #pragma unroll
    for (int k = 0; k < 14; ++k) {
        const int e = t + k * 512;            // 0..7167
        const int im = e / 1828, unit = e - im * 1828;
        const char* gp = (const char*)xt + ((size_t)(b0 + im) * 8 + icc) * XREG + unit * 16;
        __builtin_amdgcn_global_load_lds(
            (const __attribute__((address_space(1))) unsigned int*)gp,
            (__attribute__((address_space(3))) unsigned int*)(dst + e * 16),
            16, 0, 0);
    }
    if (t < 144) {
        const int e = 7168 + t;               // 7168..7311
        const int im = e / 1828, unit = e - im * 1828;
        const char* gp = (const char*)xt + ((size_t)(b0 + im) * 8 + icc) * XREG + unit * 16;
        __builtin_amdgcn_global_load_lds(
            (const __attribute__((address_space(1))) unsigned int*)gp,
            (__attribute__((address_space(3))) unsigned int*)(dst + e * 16),
            16, 0, 0);
    }
}

// ---------------------------------------------------------------------------
// conv2 via MFMA, oc-split: grid 256 = 128 quads (4 img) x 2 oc-halves.
// 512 thr = 8 waves: wr = wid>>1 (img), wc = wid&1 (oc-64-group in half).
// B per block = 5.3 MB (half) -> halves per-CU L2 traffic vs R11.
// A single-buffered 117KB LDS, 2 barriers per icc.
// ---------------------------------------------------------------------------
__global__ __launch_bounds__(512, 1) void k_conv2(const __hip_bfloat16* __restrict__ xt,
                                                  const __hip_bfloat16* __restrict__ Bw2,
                                                  const float* __restrict__ pcb,
                                                  float* __restrict__ u)
{
    const int quad = blockIdx.x >> 1;
    const int ochalf = blockIdx.x & 1;
    const int b0 = quad * 4;
    const int t = threadIdx.x;
    const int lane = t & 63, wid = t >> 6;
    const int wr = wid >> 1, wc = wid & 1;
    const int WC = ochalf * 2 + wc;          // global 64-oc group 0..3
    const int r16 = lane & 15, slot = lane >> 4;

    __shared__ alignas(16) char xs[4 * 29248];   // 117KB, images contiguous

    int lc[3];
    #pragma unroll
    for (int mt = 0; mt < 3; ++mt) {
        int hw = mt * 16 + r16;
        if (hw >= 36) hw = 0;
        int h = hw / 6, w = hw - h * 6;
        lc[mt] = 46 * h + w;               // 46 = 2*23 (output stride-2 rows)
    }
    const int abase0 = wr * XREG + slot * XSLOT;

    float4v acc[3][4];
    #pragma unroll
    for (int mt = 0; mt < 3; ++mt)
        #pragma unroll
        for (int nt = 0; nt < 4; ++nt)
            acc[mt][nt] = (float4v){0.f, 0.f, 0.f, 0.f};

    for (int icc = 0; icc < 8; ++icc) {
        __syncthreads();                       // waves done reading xs
        stage_x4(xt, xs, b0, icc, t);
        __syncthreads();                       // stage complete (vmcnt drained)

        const char* xw = xs;
        const char* ap0 = xw + abase0 + lc[0] * 16;
        const char* ap1 = xw + abase0 + lc[1] * 16;
        const char* ap2 = xw + abase0 + lc[2] * 16;
        const __hip_bfloat16* bp = Bw2 + ((size_t)icc * 4 + WC) * 2048 + lane * 8;

        for (int ky = 0; ky < 9; ++ky) {
            const int rb = (23 * ky) * 16;
            const __hip_bfloat16* bk = bp + (size_t)ky * 9 * 65536;
            #pragma unroll
            for (int kx = 0; kx < 9; ++kx) {
                const int C = rb + (10 * (kx & 1) + (kx >> 1)) * 16;
                short8v a0 = *(const short8v*)(ap0 + C);
                short8v a1 = *(const short8v*)(ap1 + C);
                short8v a2 = *(const short8v*)(ap2 + C);
                const __hip_bfloat16* bq = bk + (size_t)kx * 65536;
                short8v bv0 = *(const short8v*)(bq);
                short8v bv1 = *(const short8v*)(bq + 512);
                short8v bv2 = *(const short8v*)(bq + 1024);
                short8v bv3 = *(const short8v*)(bq + 1536);
                acc[0][0] = __builtin_amdgcn_mfma_f32_16x16x32_bf16(a0, bv0, acc[0][0], 0, 0, 0);
                acc[0][1] = __builtin_amdgcn_mfma_f32_16x16x32_bf16(a0, bv1, acc[0][1], 0, 0, 0);
                acc[0][2] = __builtin_amdgcn_mfma_f32_16x16x32_bf16(a0, bv2, acc[0][2], 0, 0, 0);
                acc[0][3] = __builtin_amdgcn_mfma_f32_16x16x32_bf16(a0, bv3, acc[0][3], 0, 0, 0);
                acc[1][0] = __builtin_amdgcn_mfma_f32_16x16x32_bf16(a1, bv0, acc[1][0], 0, 0, 0);
                acc[1][1] = __builtin_amdgcn_mfma_f32_16x16x32_bf16(a1, bv1, acc[1][1], 0, 0, 0);
                acc[1][2] = __builtin_amdgcn_mfma_f32_16x16x32_bf16(a1, bv2, acc[1][2], 0, 0, 0);
                acc[1][3] = __builtin_amdgcn_mfma_f32_16x16x32_bf16(a1, bv3, acc[1][3], 0, 0, 0);
                acc[2][0] = __builtin_amdgcn_mfma_f32_16x16x32_bf16(a2, bv0, acc[2][0], 0, 0, 0);
                acc[2][1] = __builtin_amdgcn_mfma_f32_16x16x32_bf16(a2, bv1, acc[2][1], 0, 0, 0);
                acc[2][2] = __builtin_amdgcn_mfma_f32_16x16x32_bf16(a2, bv2, acc[2][2], 0, 0, 0);
                acc[2][3] = __builtin_amdgcn_mfma_f32_16x16x32_bf16(a2, bv3, acc[2][3], 0, 0, 0);
            }
        }
    }

    // epilogue: D row(hw) = slot*4+i, col(oc) = r16
    const int b = b0 + wr;
    #pragma unroll
    for (int mt = 0; mt < 3; ++mt) {
        int hwb = mt * 16 + slot * 4;
        if (hwb < 36) {
            #pragma unroll
            for (int nt = 0; nt < 4; ++nt) {
                int oc = ochalf * 128 + wc * 64 + nt * 16 + r16;
                float pb = pcb[oc];
                float4v v = acc[mt][nt];
                v.x += pb; v.y += pb; v.z += pb; v.w += pb;
                *(float4v*)(u + (size_t)b * 9216 + oc * 36 + hwb) = v;
            }
        }
    }
}

// ---------------------------------------------------------------------------
// squash groups of 8 (in place)
// ---------------------------------------------------------------------------
__global__ void k_squash_u(float* __restrict__ u, int ngroups)
{
    int g = blockIdx.x * blockDim.x + threadIdx.x;
    if (g >= ngroups) return;
    float4v* p = (float4v*)(u + (size_t)g * 8);
    float4v a = p[0], c = p[1];
    float sq = a.x * a.x + a.y * a.y + a.z * a.z + a.w * a.w
             + c.x * c.x + c.y * c.y + c.z * c.z + c.w * c.w;
    float scale = (sq / (1.f + sq)) / sqrtf(sq + EPSF);
    a *= scale; c *= scale;
    p[0] = a; p[1] = c;
}

// ---------------------------------------------------------------------------
// routing: grid 1152 = 144 rc (8 W-rows) x 8 bc (64 images); 256 thr.
// Thread = (oq quarter, image); r-loop serial -> NO cross-lane r-reduce.
// ---------------------------------------------------------------------------
__global__ __launch_bounds__(256, 2) void k_route3(const float* __restrict__ u,
                                                   const float* __restrict__ W,
                                                   const float* __restrict__ vsum,
                                                   float* __restrict__ spart, int iter)
{
    const int bid = blockIdx.x;
    const int rc = bid % 144;
    const int bc = bid / 144;
    const int r0 = rc * 8;
    const int b0 = bc * 64;
    const int t = threadIdx.x;
    const int oq = t & 3;
    const int img = t >> 2;           // 0..63
    const int b = b0 + img;

    __shared__ alignas(16) float Wl[10240];    // 40KB: 8 rows x 320 f4 units, swizzled
    __shared__ alignas(16) float ul[64 * 68];  // 17.4KB: u tile, padded stride 68

    #pragma unroll
    for (int k = 0; k < 10; ++k) {
        int e = t + k * 256;
        int rr = e / 320, rest = e - rr * 320;
        float4v val = *(const float4v*)(W + (size_t)(r0 + rr) * 1280 + rest * 4);
        int es = e ^ ((e >> 3) & 3);
        *(float4v*)(Wl + es * 4) = val;
    }
    #pragma unroll
    for (int k = 0; k < 4; ++k) {
        int e = t + k * 256;
        int im = e >> 4, f4 = e & 15;
        float4v val = *(const float4v*)(u + (size_t)(b0 + im) * 9216 + rc * 64 + f4 * 4);
        *(float4v*)(ul + im * 68 + f4 * 4) = val;
    }
    __syncthreads();

    float4v vv[10];
    if (iter > 0) {
        #pragma unroll
        for (int j = 0; j < 10; ++j)
            vv[j] = *(const float4v*)(vsum + (size_t)b * 160 + j * 16 + oq * 4);
    }

    float4v acc[10];
    #pragma unroll
    for (int j = 0; j < 10; ++j) acc[j] = (float4v){0.f, 0.f, 0.f, 0.f};

    const float* up = ul + img * 68;

    for (int r = 0; r < 8; ++r) {
        float4v u0 = *(const float4v*)(up + r * 8);
        float4v u1 = *(const float4v*)(up + r * 8 + 4);
        float4v uh[10];
        #pragma unroll
        for (int j = 0; j < 10; ++j) {
            #pragma unroll
            for (int oo = 0; oo < 4; ++oo) {
                int un = r * 320 + j * 32 + oq * 8 + oo * 2;
                int i0 = un ^ oq;
                int i1 = i0 ^ 1;
                float4v wlo = *(const float4v*)(Wl + i0 * 4);
                float4v whi = *(const float4v*)(Wl + i1 * 4);
                uh[j][oo] = wlo.x * u0.x + wlo.y * u0.y + wlo.z * u0.z + wlo.w * u0.w
                          + whi.x * u1.x + whi.y * u1.y + whi.z * u1.z + whi.w * u1.w;
            }
        }
        if (iter > 0) {
            float q[10];
            #pragma unroll
            for (int j = 0; j < 10; ++j) {
                float qp = uh[j].x * vv[j].x + uh[j].y * vv[j].y
                         + uh[j].z * vv[j].z + uh[j].w * vv[j].w;
                qp += __shfl_xor(qp, 1);
                qp += __shfl_xor(qp, 2);
                q[j] = qp;
            }
            float mx = q[0];
            #pragma unroll
            for (int j = 1; j < 10; ++j) mx = fmaxf(mx, q[j]);
            float ssum = 0.f;
            float c[10];
            #pragma unroll
            for (int j = 0; j < 10; ++j) { c[j] = __expf(q[j] - mx); ssum += c[j]; }
            float inv = 1.f / ssum;
            #pragma unroll
            for (int j = 0; j < 10; ++j) acc[j] += (c[j] * inv) * uh[j];
        } else {
            #pragma unroll
            for (int j = 0; j < 10; ++j) acc[j] += 0.1f * uh[j];
        }
    }

    float* dst = spart + ((size_t)rc * 512 + b) * 160 + oq * 4;
    #pragma unroll
    for (int j = 0; j < 10; ++j)
        *(float4v*)(dst + j * 16) = acc[j];
}

// ---------------------------------------------------------------------------
// finish: sum 144 partials -> squash -> v; vsum update; iter==2 writes outputs
// ---------------------------------------------------------------------------
__global__ void k_finish(const float* __restrict__ spart, float* __restrict__ vsum,
                         const int* __restrict__ label, float* __restrict__ obj,
                         float* __restrict__ yprob, float* __restrict__ masked, int iter)
{
    const int b = blockIdx.x, t = threadIdx.x;
    if (t < 160) {
        const float* sp = spart + (size_t)b * 160 + t;
        float sv = 0.f;
        #pragma unroll 8
        for (int rc = 0; rc < 144; ++rc)
            sv += sp[(size_t)rc * 81920];
        float sq = sv * sv;
        sq += __shfl_xor(sq, 1); sq += __shfl_xor(sq, 2);
        sq += __shfl_xor(sq, 4); sq += __shfl_xor(sq, 8);
        float v = sv * (sq / (1.f + sq)) / sqrtf(sq + EPSF);
        float pv = (iter > 0) ? vsum[b * 160 + t] : 0.f;
        vsum[b * 160 + t] = pv + v;
        if (iter == 2) {
            obj[b * 160 + t] = v;
            float vv = v * v;
            vv += __shfl_xor(vv, 1); vv += __shfl_xor(vv, 2);
            vv += __shfl_xor(vv, 4); vv += __shfl_xor(vv, 8);
            int j = t >> 4;
            if ((t & 15) == 0) yprob[b * 10 + j] = sqrtf(vv + EPSF);
            masked[b * 160 + t] = (label[b] == j) ? v : 0.f;
        }
    }
}

// ---------------------------------------------------------------------------
// decoder GEMM: C[m,n] = act(bias[n] + sum_k A[m,k]*Wt[n,k]); M=512.
// ---------------------------------------------------------------------------
__global__ void k_mlp(const float* __restrict__ A, const float* __restrict__ Wt,
                      const float* __restrict__ bias, float* __restrict__ C,
                      int N, int K, int act)
{
    const int m0 = blockIdx.x * 32;
    const int n0 = blockIdx.y * 32;
    const int t  = threadIdx.x;
    const int tn = t & 31, tg = t >> 5;
    __shared__ float As[32][33];
    __shared__ float Ws[32][33];
    float acc[4] = {0.f, 0.f, 0.f, 0.f};
    for (int k0 = 0; k0 < K; k0 += 32) {
        __syncthreads();
        for (int idx = t; idx < 1024; idx += 256) {
            int rr = idx >> 5, kk = idx & 31;
            As[rr][kk] = A[(size_t)(m0 + rr) * K + k0 + kk];
            int n = n0 + rr;
            Ws[rr][kk] = (n < N) ? Wt[(size_t)n * K + k0 + kk] : 0.f;
        }
        __syncthreads();
        #pragma unroll 8
        for (int kk = 0; kk < 32; ++kk) {
            float bv = Ws[tn][kk];
            #pragma unroll
            for (int i = 0; i < 4; ++i)
                acc[i] += As[tg * 4 + i][kk] * bv;
        }
    }
    int n = n0 + tn;
    if (n < N) {
        float bs = bias[n];
        #pragma unroll
        for (int i = 0; i < 4; ++i) {
            float vv = acc[i] + bs;
            vv = (act == 0) ? fmaxf(vv, 0.f) : 1.f / (1.f + expf(-vv));
            C[(size_t)(m0 + tg * 4 + i) * N + n] = vv;
        }
    }
}

// ---------------------------------------------------------------------------
extern "C" void kernel_launch(void* const* d_in, const int* in_sizes, int n_in,
                              void* d_out, int out_size, void* d_ws, size_t ws_size,
                              hipStream_t stream)
{
    const float* image  = (const float*)d_in[0];
    const int*   label  = (const int*)  d_in[1];
    const float* conv_w = (const float*)d_in[2];
    const float* conv_b = (const float*)d_in[3];
    const float* pc_w   = (const float*)d_in[4];
    const float* pc_b   = (const float*)d_in[5];
    const float* Wrt    = (const float*)d_in[6];
    const float* dw1 = (const float*)d_in[7];
    const float* db1 = (const float*)d_in[8];
    const float* dw2 = (const float*)d_in[9];
    const float* db2 = (const float*)d_in[10];
    const float* dw3 = (const float*)d_in[11];
    const float* db3 = (const float*)d_in[12];
    float* out = (float*)d_out;

    char* p = (char*)d_ws;
    __hip_bfloat16* xt  = (__hip_bfloat16*)p; p += (size_t)512 * 8 * XREG; // 119.8 MB
    float* u      = (float*)p; p += 18874368;
    __hip_bfloat16* Bw2 = (__hip_bfloat16*)p; p += 10616832;
    float* vsum   = (float*)p; p += 327680;
    float* masked = (float*)p; p += 327680;
    float* h1     = (float*)p; p += 1048576;
    float* h2     = (float*)p; p += 2097152;

    // spart [144][512][160] f32 (47.2 MB) aliases xt (dead after k_conv2,
    // fully rewritten by conv1 each launch -> deterministic across replays).
    float* spart = (float*)xt;

    float* obj   = out;            // [512,10,16,1]
    float* recon = out + 81920;    // [512,1,28,28]
    float* yprob = out + 483328;   // [512,10]

    k_bw2<<<256, 256, 0, stream>>>(pc_w, Bw2);
    k_conv1<<<512, 256, 0, stream>>>(image, conv_w, conv_b, xt);
    k_conv2<<<256, 512, 0, stream>>>(xt, Bw2, pc_b, u);
    k_squash_u<<<2304, 256, 0, stream>>>(u, 589824);
    for (int it = 0; it < 3; ++it) {
        k_route3<<<1152, 256, 0, stream>>>(u, Wrt, vsum, spart, it);
        k_finish<<<512, 192, 0, stream>>>(spart, vsum, label, obj, yprob, masked, it);
    }
    k_mlp<<<dim3(16, 16), 256, 0, stream>>>(masked, dw1, db1, h1, 512, 160, 0);
    k_mlp<<<dim3(16, 32), 256, 0, stream>>>(h1, dw2, db2, h2, 1024, 512, 0);
    k_mlp<<<dim3(16, 25), 256, 0, stream>>>(h2, dw3, db3, recon, 784, 1024, 1);
}